// Round 21
// baseline (228.551 us; speedup 1.0000x reference)
//
#include <hip/hip_runtime.h>
#include <hip/hip_bf16.h>

#define FDIM 64
#define LFP 128
#define RROUNDS 4
#define BM 64       // nodes per block in round kernel
#define PCHUNK 4096 // edges per partition block
#define CB 512      // nodes per coarse bucket
#define MAXB 10240  // capacity per coarse bucket region (mean 8163, ~23 sigma)
#define RSL 32      // slices per reduce block

typedef __attribute__((ext_vector_type(8))) short bf16x8;
typedef __attribute__((ext_vector_type(4))) float f32x4;
typedef __attribute__((ext_vector_type(2))) unsigned int u32x2;

__device__ __forceinline__ float bf2f(unsigned short u) {
    unsigned int x = ((unsigned int)u) << 16;
    float f;
    __builtin_memcpy(&f, &x, 4);
    return f;
}
__device__ __forceinline__ unsigned short f2bf(float x) {
    unsigned int u;
    __builtin_memcpy(&u, &x, 4);
    unsigned int r = (u + 0x7fffu + ((u >> 16) & 1u)) >> 16;  // RNE
    return (unsigned short)r;
}

// fp8 e4m3 (OCP) helpers — native v_cvt on gfx950
__device__ __forceinline__ void acc8(float* acc, u32x2 u, float m) {
    acc[0] = fmaf(m, __builtin_amdgcn_cvt_f32_fp8(u[0], 0), acc[0]);
    acc[1] = fmaf(m, __builtin_amdgcn_cvt_f32_fp8(u[0], 1), acc[1]);
    acc[2] = fmaf(m, __builtin_amdgcn_cvt_f32_fp8(u[0], 2), acc[2]);
    acc[3] = fmaf(m, __builtin_amdgcn_cvt_f32_fp8(u[0], 3), acc[3]);
    acc[4] = fmaf(m, __builtin_amdgcn_cvt_f32_fp8(u[1], 0), acc[4]);
    acc[5] = fmaf(m, __builtin_amdgcn_cvt_f32_fp8(u[1], 1), acc[5]);
    acc[6] = fmaf(m, __builtin_amdgcn_cvt_f32_fp8(u[1], 2), acc[6]);
    acc[7] = fmaf(m, __builtin_amdgcn_cvt_f32_fp8(u[1], 3), acc[7]);
}
__device__ __forceinline__ void dec8(u32x2 u, float* f) {
    f[0] = __builtin_amdgcn_cvt_f32_fp8(u[0], 0);
    f[1] = __builtin_amdgcn_cvt_f32_fp8(u[0], 1);
    f[2] = __builtin_amdgcn_cvt_f32_fp8(u[0], 2);
    f[3] = __builtin_amdgcn_cvt_f32_fp8(u[0], 3);
    f[4] = __builtin_amdgcn_cvt_f32_fp8(u[1], 0);
    f[5] = __builtin_amdgcn_cvt_f32_fp8(u[1], 1);
    f[6] = __builtin_amdgcn_cvt_f32_fp8(u[1], 2);
    f[7] = __builtin_amdgcn_cvt_f32_fp8(u[1], 3);
}
__device__ __forceinline__ u32x2 pack8(const float* f) {
    unsigned int w0 = 0, w1 = 0;
    w0 = (unsigned int)__builtin_amdgcn_cvt_pk_fp8_f32(f[0], f[1], (int)w0, false);
    w0 = (unsigned int)__builtin_amdgcn_cvt_pk_fp8_f32(f[2], f[3], (int)w0, true);
    w1 = (unsigned int)__builtin_amdgcn_cvt_pk_fp8_f32(f[4], f[5], (int)w1, false);
    w1 = (unsigned int)__builtin_amdgcn_cvt_pk_fp8_f32(f[6], f[7], (int)w1, true);
    u32x2 r; r[0] = w0; r[1] = w1;
    return r;
}

// ---------------- setup: weights->bf16 transposed + emb init (fp8) + zero counters ----
__global__ void setup_kernel(const int* __restrict__ feat, const float* __restrict__ table,
                             const float* __restrict__ Wh, const float* __restrict__ Wfp,
                             unsigned char* __restrict__ emb, unsigned short* __restrict__ whT,
                             unsigned short* __restrict__ wfpT, int* __restrict__ bucketCount,
                             int n) {
    int gid = blockIdx.x * blockDim.x + threadIdx.x;
    if (gid < RROUNDS * FDIM * FDIM) {
        int r = gid >> 12, rem = gid & 4095, j = rem >> 6, k = rem & 63;
        whT[gid] = f2bf(Wh[r * 4096 + k * 64 + j]);
    } else if (gid < RROUNDS * FDIM * FDIM + RROUNDS * LFP * FDIM) {
        int o2 = gid - RROUNDS * FDIM * FDIM;
        int r = o2 >> 13, rem = o2 & 8191, l = rem >> 6, k = rem & 63;
        wfpT[o2] = f2bf(Wfp[r * 8192 + k * 128 + l]);
    }
    if (gid < n * FDIM) {
        float v = table[feat[gid >> 6] * FDIM + (gid & 63)];
        unsigned int p = (unsigned int)__builtin_amdgcn_cvt_pk_fp8_f32(v, v, 0, false);
        emb[gid] = (unsigned char)(p & 0xFF);
    }
    if (gid < 128) bucketCount[gid] = 0;
}

// ---------------- CSR build: single-pass partition into padded bucket regions ----
__global__ __launch_bounds__(256) void partition_kernel(
        const int* __restrict__ esrc, const int* __restrict__ edst,
        int* __restrict__ bucketCount, int* __restrict__ tmp, int nE, int nbc) {
    __shared__ int scnt[128], sinc[128], sexc[128], sgbase[128], scur[128];
    __shared__ int sbuf[PCHUNK];
    __shared__ int starg[PCHUNK];
    int t = threadIdx.x;
    int c0 = blockIdx.x * PCHUNK;
    int cend = c0 + PCHUNK; if (cend > nE) cend = nE;

    if (t < 128) scnt[t] = 0;
    __syncthreads();
#pragma unroll
    for (int k = 0; k < PCHUNK / 256; ++k) {
        int idx = c0 + k * 256 + t;
        if (idx < cend) atomicAdd(&scnt[edst[idx] >> 9], 1);
    }
    __syncthreads();
    if (t < 128) sinc[t] = scnt[t];
    __syncthreads();
    for (int d = 1; d < 128; d <<= 1) {
        int x = (t >= d && t < 128) ? sinc[t - d] : 0;
        __syncthreads();
        if (t < 128) sinc[t] += x;
        __syncthreads();
    }
    if (t < 128) {
        int ex = sinc[t] - scnt[t];
        sexc[t] = ex;
        scur[t] = ex;
        sgbase[t] = (t < nbc && scnt[t] > 0)
                        ? t * MAXB + atomicAdd(&bucketCount[t], scnt[t]) : 0;
    }
    __syncthreads();
#pragma unroll
    for (int k = 0; k < PCHUNK / 256; ++k) {
        int idx = c0 + k * 256 + t;
        if (idx < cend) {
            int s = esrc[idx], d = edst[idx];
            int b = d >> 9;
            int pos = atomicAdd(&scur[b], 1);
            sbuf[pos] = (s << 9) | (d & 511);
            starg[pos] = sgbase[b] + (pos - sexc[b]);
        }
    }
    __syncthreads();
    int cnt = cend - c0;
#pragma unroll
    for (int k = 0; k < PCHUNK / 256; ++k) {
        int li = k * 256 + t;
        if (li < cnt) tmp[starg[li]] = sbuf[li];
    }
}

// per-bucket fine counting sort -> csr16 (ushort srcs) + rp
__global__ __launch_bounds__(256) void bsort_kernel(
        const int* __restrict__ bucketCount, const int* __restrict__ tmp,
        unsigned short* __restrict__ csr16, int* __restrict__ rp, int N, int nE, int nbc) {
    __shared__ unsigned short ssrc[MAXB];
    __shared__ int pcnt[CB], pexc[CB], pcur[CB];
    __shared__ int ssum[256];
    __shared__ int sS[128];
    int t = threadIdx.x;
    int b = blockIdx.x;

    if (t < 128) sS[t] = (t < nbc) ? bucketCount[t] : 0;
    __syncthreads();
    for (int d = 1; d < 128; d <<= 1) {
        int x = (t >= d && t < 128) ? sS[t - d] : 0;
        __syncthreads();
        if (t < 128) sS[t] += x;
        __syncthreads();
    }
    int lo = (b == 0) ? 0 : sS[b - 1];
    int cnt = sS[b] - lo;

    pcnt[t] = 0; pcnt[t + 256] = 0;
    __syncthreads();
    const int* bt = tmp + (size_t)b * MAXB;
    for (int idx = t; idx < cnt; idx += 256)
        atomicAdd(&pcnt[bt[idx] & 511], 1);
    __syncthreads();
    int a0 = pcnt[2 * t], a1 = pcnt[2 * t + 1];
    ssum[t] = a0 + a1;
    __syncthreads();
    for (int d = 1; d < 256; d <<= 1) {
        int x = (t >= d) ? ssum[t - d] : 0;
        __syncthreads();
        ssum[t] += x;
        __syncthreads();
    }
    int ex = ssum[t] - (a0 + a1);
    pexc[2 * t] = ex;          pcur[2 * t] = ex;
    pexc[2 * t + 1] = ex + a0; pcur[2 * t + 1] = ex + a0;
    __syncthreads();
#pragma unroll
    for (int i = t; i < CB; i += 256) {
        int node = b * CB + i;
        if (node < N) rp[node] = lo + pexc[i];
    }
    if (b == 0 && t == 0) rp[N] = nE;
    for (int idx = t; idx < cnt; idx += 256) {
        int e = bt[idx];
        int pos = atomicAdd(&pcur[e & 511], 1);
        ssrc[pos] = (unsigned short)(e >> 9);
    }
    __syncthreads();
    for (int li = t; li < cnt; li += 256) csr16[lo + li] = ssrc[li];
}

// ---------------- fused round v3: 8-wave blocks for gather TLP --------------------
// r20 lesson: per-wave ILP (node pairing) is null — gather is TLP-limited at
// 3 waves/SIMD (3128 waves grid-cap). Fix: 512-thread blocks, one wave per 8
// nodes -> 6256 waves ~ 6.1/SIMD during gather. Gather body = r19's proven
// single-node 4-deep clamped unroll. Cross-wave sV handoff -> one barrier;
// MLP phase runs on waves 0-3 only (MFMA util is ~1%, idle waves 4-7 are cheap).
__global__ __launch_bounds__(512) void round_kernel(
        const unsigned char* __restrict__ embIn, unsigned char* __restrict__ embOut,
        const int* __restrict__ rp, const unsigned short* __restrict__ csr16,
        const unsigned short* __restrict__ whT, const unsigned short* __restrict__ wfpT,
        const float* __restrict__ bh, const float* __restrict__ bfp,
        float* __restrict__ fpart, int N, int storeOut) {
    __shared__ unsigned short sV[BM * 72];  // v rows
    __shared__ unsigned short sR[BM * 72];  // r exchange
    __shared__ float sFp[4][128];

    int tid = threadIdx.x;
    int base = blockIdx.x * BM;
    int lane = tid & 63, w = tid >> 6;      // w in [0,8)
    int grp = lane >> 3, q = lane & 7;

    // this wave's 9 rp bounds for its 8 nodes
    int nodeBase = base + w * 8;
    int nn = nodeBase + lane;
    if (nn > N) nn = N;
    int rpv = (lane < 9) ? rp[nn] : 0;

    // ---- gather: wave w handles nodes nodeBase .. nodeBase+7 ----
#pragma unroll
    for (int i = 0; i < 8; ++i) {
        int node = nodeBase + i;
        int start = __shfl(rpv, i);
        int end = __shfl(rpv, i + 1);
        if (node < N) {
            int last = end - 1;
            u32x2 selfw = *reinterpret_cast<const u32x2*>(embIn + (size_t)node * 64 + q * 8);
            float acc[8] = {0.f, 0.f, 0.f, 0.f, 0.f, 0.f, 0.f, 0.f};
            for (int j = start + grp; j < end; j += 32) {
                int j1 = j + 8, j2 = j + 16, j3 = j + 24;
                int c1 = j1 <= last ? j1 : last;
                int c2 = j2 <= last ? j2 : last;
                int c3 = j3 <= last ? j3 : last;
                int n0 = csr16[j];
                int n1 = csr16[c1];
                int n2 = csr16[c2];
                int n3 = csr16[c3];
                u32x2 u0 = *reinterpret_cast<const u32x2*>(embIn + (size_t)n0 * 64 + q * 8);
                u32x2 u1 = *reinterpret_cast<const u32x2*>(embIn + (size_t)n1 * 64 + q * 8);
                u32x2 u2 = *reinterpret_cast<const u32x2*>(embIn + (size_t)n2 * 64 + q * 8);
                u32x2 u3 = *reinterpret_cast<const u32x2*>(embIn + (size_t)n3 * 64 + q * 8);
                acc8(acc, u0, 1.f);
                acc8(acc, u1, (j1 <= last) ? 1.f : 0.f);
                acc8(acc, u2, (j2 <= last) ? 1.f : 0.f);
                acc8(acc, u3, (j3 <= last) ? 1.f : 0.f);
            }
#pragma unroll
            for (int x = 0; x < 8; ++x) {
                acc[x] += __shfl_xor(acc[x], 8);
                acc[x] += __shfl_xor(acc[x], 16);
                acc[x] += __shfl_xor(acc[x], 32);
            }
            if (grp == 0) {
                float sf[8];
                dec8(selfw, sf);
                bf16x8 o;
#pragma unroll
                for (int x = 0; x < 8; ++x) o[x] = (short)f2bf(acc[x] + sf[x]);
                *reinterpret_cast<bf16x8*>(sV + (w * 8 + i) * 72 + q * 8) = o;
            }
        } else if (grp == 0) {
            bf16x8 o;
#pragma unroll
            for (int x = 0; x < 8; ++x) o[x] = 0;
            *reinterpret_cast<bf16x8*>(sV + (w * 8 + i) * 72 + q * 8) = o;
        }
    }
    __syncthreads();  // cross-wave sV handoff (gather waves 2w,2w+1 -> MLP wave w)

    // ---- MLP phase: waves 0-3 only ----
    if (w < 4) {
        int m16 = lane & 15, g = lane >> 4;
        int arow = w * 16 + m16;

        bf16x8 a0 = *reinterpret_cast<const bf16x8*>(sV + arow * 72 + g * 8);
        bf16x8 a1 = *reinterpret_cast<const bf16x8*>(sV + arow * 72 + 32 + g * 8);

        f32x4 acc[4];
#pragma unroll
        for (int c = 0; c < 4; ++c) {
            bf16x8 b0 = *reinterpret_cast<const bf16x8*>(whT + (c * 16 + m16) * 64 + g * 8);
            bf16x8 b1 = *reinterpret_cast<const bf16x8*>(whT + (c * 16 + m16) * 64 + 32 + g * 8);
            f32x4 z = {0.f, 0.f, 0.f, 0.f};
            z = __builtin_amdgcn_mfma_f32_16x16x32_bf16(a0, b0, z, 0, 0, 0);
            z = __builtin_amdgcn_mfma_f32_16x16x32_bf16(a1, b1, z, 0, 0, 0);
            acc[c] = z;
        }
        // C layout: row=(lane>>4)*4+reg, col=c*16+m16
#pragma unroll
        for (int c = 0; c < 4; ++c) {
            float bias = bh[c * 16 + m16];
#pragma unroll
            for (int reg = 0; reg < 4; ++reg) {
                float rv = fmaxf(acc[c][reg] + bias, 0.f);
                sR[(w * 16 + g * 4 + reg) * 72 + c * 16 + m16] = f2bf(rv);
            }
        }

        bf16x8 ra0 = *reinterpret_cast<const bf16x8*>(sR + arow * 72 + g * 8);
        bf16x8 ra1 = *reinterpret_cast<const bf16x8*>(sR + arow * 72 + 32 + g * 8);

        if (storeOut) {
#pragma unroll
            for (int it = 0; it < 2; ++it) {
                int lidx = w * 1024 + it * 512 + lane * 8;
                int row = lidx >> 6;
                if (base + row < N) {
                    bf16x8 rv = *reinterpret_cast<const bf16x8*>(sR + row * 72 + (lidx & 63));
                    float f[8];
#pragma unroll
                    for (int x = 0; x < 8; ++x) f[x] = bf2f((unsigned short)rv[x]);
                    *reinterpret_cast<u32x2*>(embOut + (size_t)base * 64 + lidx) = pack8(f);
                }
            }
        }

        f32x4 z[8];
#pragma unroll
        for (int t = 0; t < 8; ++t) {
            bf16x8 b0 = *reinterpret_cast<const bf16x8*>(wfpT + (t * 16 + m16) * 64 + g * 8);
            bf16x8 b1 = *reinterpret_cast<const bf16x8*>(wfpT + (t * 16 + m16) * 64 + 32 + g * 8);
            f32x4 zz = {0.f, 0.f, 0.f, 0.f};
            zz = __builtin_amdgcn_mfma_f32_16x16x32_bf16(ra0, b0, zz, 0, 0, 0);
            zz = __builtin_amdgcn_mfma_f32_16x16x32_bf16(ra1, b1, zz, 0, 0, 0);
            float bias = bfp[t * 16 + m16];
#pragma unroll
            for (int reg = 0; reg < 4; ++reg) zz[reg] += bias;
            z[t] = zz;
        }

#pragma unroll
        for (int reg = 0; reg < 4; ++reg) {
            float mx = -1e30f;
#pragma unroll
            for (int t = 0; t < 8; ++t) mx = fmaxf(mx, z[t][reg]);
#pragma unroll
            for (int d = 1; d < 16; d <<= 1) mx = fmaxf(mx, __shfl_xor(mx, d));
            float s = 0.f;
#pragma unroll
            for (int t = 0; t < 8; ++t) {
                float p = __expf(z[t][reg] - mx);
                z[t][reg] = p;
                s += p;
            }
#pragma unroll
            for (int d = 1; d < 16; d <<= 1) s += __shfl_xor(s, d);
            int node = base + w * 16 + g * 4 + reg;
            float inv = (node < N) ? (1.f / s) : 0.f;
#pragma unroll
            for (int t = 0; t < 8; ++t) z[t][reg] *= inv;
        }
#pragma unroll
        for (int t = 0; t < 8; ++t) {
            float v = z[t][0] + z[t][1] + z[t][2] + z[t][3];
            v += __shfl_xor(v, 16);
            v += __shfl_xor(v, 32);
            if (g == 0) sFp[w][t * 16 + m16] = v;
        }
    }
    __syncthreads();
    if (tid < 128) {
        float s = sFp[0][tid] + sFp[1][tid] + sFp[2][tid] + sFp[3][tid];
        fpart[(size_t)blockIdx.x * 128 + tid] = s;
    }
}

// stage-1 reduce: unrolled multi-accumulator (round-9 lesson)
__global__ __launch_bounds__(256) void reduce1_kernel(const float* __restrict__ fpart,
                                                      float* __restrict__ fred, int nslice) {
    __shared__ float sAcc[128];
    int t = threadIdx.x;
    int col = t & 127, gp = t >> 7;
    int base = blockIdx.x * RSL + gp * (RSL / 2);
    const float* p = fpart + (size_t)base * 128 + col;
    float a0 = 0.f, a1 = 0.f, a2 = 0.f, a3 = 0.f;
    if (base + RSL / 2 <= nslice) {
#pragma unroll
        for (int k = 0; k < 4; ++k) {
            a0 += p[(k * 4 + 0) * 128];
            a1 += p[(k * 4 + 1) * 128];
            a2 += p[(k * 4 + 2) * 128];
            a3 += p[(k * 4 + 3) * 128];
        }
    } else {
        int cnt = nslice - base; if (cnt < 0) cnt = 0;
        for (int k = 0; k < cnt; ++k) a0 += p[k * 128];
    }
    float s = (a0 + a1) + (a2 + a3);
    if (gp == 1) sAcc[col] = s;
    __syncthreads();
    if (gp == 0) fred[(size_t)blockIdx.x * 128 + col] = s + sAcc[col];
}

__global__ __launch_bounds__(256) void final_kernel(const float* __restrict__ fred, int nred,
                                                    const float* __restrict__ Wcl,
                                                    const float* __restrict__ bcl,
                                                    float* __restrict__ out) {
    __shared__ float sAcc[128];
    __shared__ float sf[128];
    __shared__ float logits[10];
    int t = threadIdx.x;
    int col = t & 127, gp = t >> 7;
    int half = (nred + 1) >> 1;
    int b0 = gp * half;
    int b1 = b0 + half; if (b1 > nred) b1 = nred;
    float a0 = 0.f, a1 = 0.f, a2 = 0.f, a3 = 0.f;
    const float* p = fred + col;
    int b = b0;
    for (; b + 4 <= b1; b += 4) {
        a0 += p[(size_t)(b + 0) * 128];
        a1 += p[(size_t)(b + 1) * 128];
        a2 += p[(size_t)(b + 2) * 128];
        a3 += p[(size_t)(b + 3) * 128];
    }
    for (; b < b1; ++b) a0 += p[(size_t)b * 128];
    float s = (a0 + a1) + (a2 + a3);
    if (gp == 1) sAcc[col] = s;
    __syncthreads();
    if (gp == 0) sf[col] = s + sAcc[col];
    __syncthreads();
    if (t < 10) {
        float acc = bcl[t];
        for (int l = 0; l < LFP; l++) acc = fmaf(sf[l], Wcl[l * 10 + t], acc);
        logits[t] = acc;
    }
    __syncthreads();
    if (t == 0) {
        float m = -1e30f;
        for (int i = 0; i < 10; i++) m = fmaxf(m, logits[i]);
        float e[10], s2 = 0.f;
        for (int i = 0; i < 10; i++) { e[i] = __expf(logits[i] - m); s2 += e[i]; }
        for (int i = 0; i < 10; i++) out[i] = e[i] / s2;
    }
}

extern "C" void kernel_launch(void* const* d_in, const int* in_sizes, int n_in,
                              void* d_out, int out_size, void* d_ws, size_t ws_size,
                              hipStream_t stream) {
    const int* feat = (const int*)d_in[0];
    const int* esrc = (const int*)d_in[1];
    const int* edst = (const int*)d_in[2];
    const float* table = (const float*)d_in[3];
    const float* Wh = (const float*)d_in[4];
    const float* bh = (const float*)d_in[5];
    const float* Wfp = (const float*)d_in[6];
    const float* bfp = (const float*)d_in[7];
    const float* Wcl = (const float*)d_in[8];
    const float* bcl = (const float*)d_in[9];
    float* out = (float*)d_out;
    int N = in_sizes[0];
    int nE = in_sizes[1];

    int nbm = (N + BM - 1) / BM;          // round blocks (782)
    int nbc = (N + CB - 1) / CB;          // coarse buckets (98)
    int nbp = (nE + PCHUNK - 1) / PCHUNK; // partition blocks (196)
    int nslice = RROUNDS * nbm;           // 3128
    int nred = (nslice + RSL - 1) / RSL;  // 98

    char* ws = (char*)d_ws;
    size_t off = 0;
    auto alloc = [&](size_t bytes) { void* p = ws + off; off += (bytes + 63) & ~(size_t)63; return p; };
    unsigned char* embA = (unsigned char*)alloc((size_t)N * 64);   // fp8
    unsigned char* embB = (unsigned char*)alloc((size_t)N * 64);   // fp8
    unsigned short* whT  = (unsigned short*)alloc(RROUNDS * 64 * 64 * 2);
    unsigned short* wfpT = (unsigned short*)alloc(RROUNDS * 128 * 64 * 2);
    float* fpart = (float*)alloc((size_t)nslice * 128 * 4);
    float* fred  = (float*)alloc((size_t)nred * 128 * 4);
    int* bucketCount = (int*)alloc(128 * 4);
    int* rp      = (int*)alloc(((size_t)N + 1) * 4);
    int* tmp     = (int*)alloc((size_t)nbc * MAXB * 4);
    unsigned short* csr16 = (unsigned short*)alloc((size_t)nE * 2);

    // setup first: zeroes bucketCount (stream-serial before partition)
    setup_kernel<<<(N * FDIM + 255) / 256, 256, 0, stream>>>(
        feat, table, Wh, Wfp, embA, whT, wfpT, bucketCount, N);

    // single-pass CSR build (rebuilt every call — deterministic, no cross-call state)
    partition_kernel<<<nbp, 256, 0, stream>>>(esrc, edst, bucketCount, tmp, nE, nbc);
    bsort_kernel<<<nbc, 256, 0, stream>>>(bucketCount, tmp, csr16, rp, N, nE, nbc);

    unsigned char* eIn = embA;
    unsigned char* eOut = embB;
    for (int r = 0; r < RROUNDS; ++r) {
        round_kernel<<<nbm, 512, 0, stream>>>(
            eIn, eOut, rp, csr16, whT + (size_t)r * 4096, wfpT + (size_t)r * 8192,
            bh + (size_t)r * FDIM, bfp + (size_t)r * LFP,
            fpart + (size_t)r * nbm * 128, N, (r < RROUNDS - 1) ? 1 : 0);
        unsigned char* t = eIn; eIn = eOut; eOut = t;
    }

    reduce1_kernel<<<nred, 256, 0, stream>>>(fpart, fred, nslice);
    final_kernel<<<1, 256, 0, stream>>>(fred, nred, Wcl, bcl, out);
}

// Round 22
// 206.674 us; speedup vs baseline: 1.1059x; 1.1059x over previous
//
#include <hip/hip_runtime.h>
#include <hip/hip_bf16.h>

#define FDIM 64
#define LFP 128
#define RROUNDS 4
#define BM 64       // nodes per block in round kernel
#define PCHUNK 4096 // edges per partition block
#define CB 512      // nodes per coarse bucket
#define MAXB 10240  // capacity per coarse bucket region (mean 8163, ~23 sigma)
#define RSL 32      // slices per reduce block

typedef __attribute__((ext_vector_type(8))) short bf16x8;
typedef __attribute__((ext_vector_type(4))) float f32x4;
typedef __attribute__((ext_vector_type(2))) unsigned int u32x2;

__device__ __forceinline__ float bf2f(unsigned short u) {
    unsigned int x = ((unsigned int)u) << 16;
    float f;
    __builtin_memcpy(&f, &x, 4);
    return f;
}
__device__ __forceinline__ unsigned short f2bf(float x) {
    unsigned int u;
    __builtin_memcpy(&u, &x, 4);
    unsigned int r = (u + 0x7fffu + ((u >> 16) & 1u)) >> 16;  // RNE
    return (unsigned short)r;
}

// fp8 e4m3 (OCP) helpers — native v_cvt on gfx950
__device__ __forceinline__ void acc8(float* acc, u32x2 u, float m) {
    acc[0] = fmaf(m, __builtin_amdgcn_cvt_f32_fp8(u[0], 0), acc[0]);
    acc[1] = fmaf(m, __builtin_amdgcn_cvt_f32_fp8(u[0], 1), acc[1]);
    acc[2] = fmaf(m, __builtin_amdgcn_cvt_f32_fp8(u[0], 2), acc[2]);
    acc[3] = fmaf(m, __builtin_amdgcn_cvt_f32_fp8(u[0], 3), acc[3]);
    acc[4] = fmaf(m, __builtin_amdgcn_cvt_f32_fp8(u[1], 0), acc[4]);
    acc[5] = fmaf(m, __builtin_amdgcn_cvt_f32_fp8(u[1], 1), acc[5]);
    acc[6] = fmaf(m, __builtin_amdgcn_cvt_f32_fp8(u[1], 2), acc[6]);
    acc[7] = fmaf(m, __builtin_amdgcn_cvt_f32_fp8(u[1], 3), acc[7]);
}
__device__ __forceinline__ void dec8(u32x2 u, float* f) {
    f[0] = __builtin_amdgcn_cvt_f32_fp8(u[0], 0);
    f[1] = __builtin_amdgcn_cvt_f32_fp8(u[0], 1);
    f[2] = __builtin_amdgcn_cvt_f32_fp8(u[0], 2);
    f[3] = __builtin_amdgcn_cvt_f32_fp8(u[0], 3);
    f[4] = __builtin_amdgcn_cvt_f32_fp8(u[1], 0);
    f[5] = __builtin_amdgcn_cvt_f32_fp8(u[1], 1);
    f[6] = __builtin_amdgcn_cvt_f32_fp8(u[1], 2);
    f[7] = __builtin_amdgcn_cvt_f32_fp8(u[1], 3);
}
__device__ __forceinline__ u32x2 pack8(const float* f) {
    unsigned int w0 = 0, w1 = 0;
    w0 = (unsigned int)__builtin_amdgcn_cvt_pk_fp8_f32(f[0], f[1], (int)w0, false);
    w0 = (unsigned int)__builtin_amdgcn_cvt_pk_fp8_f32(f[2], f[3], (int)w0, true);
    w1 = (unsigned int)__builtin_amdgcn_cvt_pk_fp8_f32(f[4], f[5], (int)w1, false);
    w1 = (unsigned int)__builtin_amdgcn_cvt_pk_fp8_f32(f[6], f[7], (int)w1, true);
    u32x2 r; r[0] = w0; r[1] = w1;
    return r;
}

// ---------------- setup: weights->bf16 transposed + emb init (fp8) + zero counters ----
__global__ void setup_kernel(const int* __restrict__ feat, const float* __restrict__ table,
                             const float* __restrict__ Wh, const float* __restrict__ Wfp,
                             unsigned char* __restrict__ emb, unsigned short* __restrict__ whT,
                             unsigned short* __restrict__ wfpT, int* __restrict__ bucketCount,
                             int n) {
    int gid = blockIdx.x * blockDim.x + threadIdx.x;
    if (gid < RROUNDS * FDIM * FDIM) {
        int r = gid >> 12, rem = gid & 4095, j = rem >> 6, k = rem & 63;
        whT[gid] = f2bf(Wh[r * 4096 + k * 64 + j]);
    } else if (gid < RROUNDS * FDIM * FDIM + RROUNDS * LFP * FDIM) {
        int o2 = gid - RROUNDS * FDIM * FDIM;
        int r = o2 >> 13, rem = o2 & 8191, l = rem >> 6, k = rem & 63;
        wfpT[o2] = f2bf(Wfp[r * 8192 + k * 128 + l]);
    }
    if (gid < n * FDIM) {
        float v = table[feat[gid >> 6] * FDIM + (gid & 63)];
        unsigned int p = (unsigned int)__builtin_amdgcn_cvt_pk_fp8_f32(v, v, 0, false);
        emb[gid] = (unsigned char)(p & 0xFF);
    }
    if (gid < 128) bucketCount[gid] = 0;
}

// ---------------- CSR build: single-pass partition into padded bucket regions ----
__global__ __launch_bounds__(256) void partition_kernel(
        const int* __restrict__ esrc, const int* __restrict__ edst,
        int* __restrict__ bucketCount, int* __restrict__ tmp, int nE, int nbc) {
    __shared__ int scnt[128], sinc[128], sexc[128], sgbase[128], scur[128];
    __shared__ int sbuf[PCHUNK];
    __shared__ int starg[PCHUNK];
    int t = threadIdx.x;
    int c0 = blockIdx.x * PCHUNK;
    int cend = c0 + PCHUNK; if (cend > nE) cend = nE;

    if (t < 128) scnt[t] = 0;
    __syncthreads();
#pragma unroll
    for (int k = 0; k < PCHUNK / 256; ++k) {
        int idx = c0 + k * 256 + t;
        if (idx < cend) atomicAdd(&scnt[edst[idx] >> 9], 1);
    }
    __syncthreads();
    if (t < 128) sinc[t] = scnt[t];
    __syncthreads();
    for (int d = 1; d < 128; d <<= 1) {
        int x = (t >= d && t < 128) ? sinc[t - d] : 0;
        __syncthreads();
        if (t < 128) sinc[t] += x;
        __syncthreads();
    }
    if (t < 128) {
        int ex = sinc[t] - scnt[t];
        sexc[t] = ex;
        scur[t] = ex;
        sgbase[t] = (t < nbc && scnt[t] > 0)
                        ? t * MAXB + atomicAdd(&bucketCount[t], scnt[t]) : 0;
    }
    __syncthreads();
#pragma unroll
    for (int k = 0; k < PCHUNK / 256; ++k) {
        int idx = c0 + k * 256 + t;
        if (idx < cend) {
            int s = esrc[idx], d = edst[idx];
            int b = d >> 9;
            int pos = atomicAdd(&scur[b], 1);
            sbuf[pos] = (s << 9) | (d & 511);
            starg[pos] = sgbase[b] + (pos - sexc[b]);
        }
    }
    __syncthreads();
    int cnt = cend - c0;
#pragma unroll
    for (int k = 0; k < PCHUNK / 256; ++k) {
        int li = k * 256 + t;
        if (li < cnt) tmp[starg[li]] = sbuf[li];
    }
}

// per-bucket fine counting sort -> csr16 (ushort srcs) + rp
__global__ __launch_bounds__(256) void bsort_kernel(
        const int* __restrict__ bucketCount, const int* __restrict__ tmp,
        unsigned short* __restrict__ csr16, int* __restrict__ rp, int N, int nE, int nbc) {
    __shared__ unsigned short ssrc[MAXB];
    __shared__ int pcnt[CB], pexc[CB], pcur[CB];
    __shared__ int ssum[256];
    __shared__ int sS[128];
    int t = threadIdx.x;
    int b = blockIdx.x;

    if (t < 128) sS[t] = (t < nbc) ? bucketCount[t] : 0;
    __syncthreads();
    for (int d = 1; d < 128; d <<= 1) {
        int x = (t >= d && t < 128) ? sS[t - d] : 0;
        __syncthreads();
        if (t < 128) sS[t] += x;
        __syncthreads();
    }
    int lo = (b == 0) ? 0 : sS[b - 1];
    int cnt = sS[b] - lo;

    pcnt[t] = 0; pcnt[t + 256] = 0;
    __syncthreads();
    const int* bt = tmp + (size_t)b * MAXB;
    for (int idx = t; idx < cnt; idx += 256)
        atomicAdd(&pcnt[bt[idx] & 511], 1);
    __syncthreads();
    int a0 = pcnt[2 * t], a1 = pcnt[2 * t + 1];
    ssum[t] = a0 + a1;
    __syncthreads();
    for (int d = 1; d < 256; d <<= 1) {
        int x = (t >= d) ? ssum[t - d] : 0;
        __syncthreads();
        ssum[t] += x;
        __syncthreads();
    }
    int ex = ssum[t] - (a0 + a1);
    pexc[2 * t] = ex;          pcur[2 * t] = ex;
    pexc[2 * t + 1] = ex + a0; pcur[2 * t + 1] = ex + a0;
    __syncthreads();
#pragma unroll
    for (int i = t; i < CB; i += 256) {
        int node = b * CB + i;
        if (node < N) rp[node] = lo + pexc[i];
    }
    if (b == 0 && t == 0) rp[N] = nE;
    for (int idx = t; idx < cnt; idx += 256) {
        int e = bt[idx];
        int pos = atomicAdd(&pcur[e & 511], 1);
        ssrc[pos] = (unsigned short)(e >> 9);
    }
    __syncthreads();
    for (int li = t; li < cnt; li += 256) csr16[lo + li] = ssrc[li];
}

// ---------------- fused round (r19 best-measured): per-wave gather (fp8) + MFMA MLP --
// r20/r21 lessons: pair-ILP and 8-wave TLP both regress; this single-node
// 4-deep clamped form is the measured optimum for the latency-bound gather.
__global__ __launch_bounds__(256) void round_kernel(
        const unsigned char* __restrict__ embIn, unsigned char* __restrict__ embOut,
        const int* __restrict__ rp, const unsigned short* __restrict__ csr16,
        const unsigned short* __restrict__ whT, const unsigned short* __restrict__ wfpT,
        const float* __restrict__ bh, const float* __restrict__ bfp,
        float* __restrict__ fpart, int N, int storeOut) {
    __shared__ unsigned short sV[BM * 72];  // v rows (own-wave strip handoff)
    __shared__ unsigned short sR[BM * 72];  // r exchange
    __shared__ float sFp[4][128];

    int tid = threadIdx.x;
    int base = blockIdx.x * BM;
    int lane = tid & 63, w = tid >> 6;
    int grp = lane >> 3, q = lane & 7;

    int nn = base + w * 16 + lane;
    if (nn > N) nn = N;
    int rpv = (lane < 17) ? rp[nn] : 0;

#pragma unroll
    for (int i = 0; i < 16; ++i) {
        int node = base + w * 16 + i;
        int start = __shfl(rpv, i);
        int end = __shfl(rpv, i + 1);
        if (node < N) {
            int last = end - 1;
            u32x2 selfw = *reinterpret_cast<const u32x2*>(embIn + (size_t)node * 64 + q * 8);
            float acc[8] = {0.f, 0.f, 0.f, 0.f, 0.f, 0.f, 0.f, 0.f};
            for (int j = start + grp; j < end; j += 32) {
                int j1 = j + 8, j2 = j + 16, j3 = j + 24;
                int c1 = j1 <= last ? j1 : last;
                int c2 = j2 <= last ? j2 : last;
                int c3 = j3 <= last ? j3 : last;
                int n0 = csr16[j];
                int n1 = csr16[c1];
                int n2 = csr16[c2];
                int n3 = csr16[c3];
                u32x2 u0 = *reinterpret_cast<const u32x2*>(embIn + (size_t)n0 * 64 + q * 8);
                u32x2 u1 = *reinterpret_cast<const u32x2*>(embIn + (size_t)n1 * 64 + q * 8);
                u32x2 u2 = *reinterpret_cast<const u32x2*>(embIn + (size_t)n2 * 64 + q * 8);
                u32x2 u3 = *reinterpret_cast<const u32x2*>(embIn + (size_t)n3 * 64 + q * 8);
                acc8(acc, u0, 1.f);
                acc8(acc, u1, (j1 <= last) ? 1.f : 0.f);
                acc8(acc, u2, (j2 <= last) ? 1.f : 0.f);
                acc8(acc, u3, (j3 <= last) ? 1.f : 0.f);
            }
#pragma unroll
            for (int x = 0; x < 8; ++x) {
                acc[x] += __shfl_xor(acc[x], 8);
                acc[x] += __shfl_xor(acc[x], 16);
                acc[x] += __shfl_xor(acc[x], 32);
            }
            if (grp == 0) {
                float sf[8];
                dec8(selfw, sf);
                bf16x8 o;
#pragma unroll
                for (int x = 0; x < 8; ++x) o[x] = (short)f2bf(acc[x] + sf[x]);
                *reinterpret_cast<bf16x8*>(sV + (w * 16 + i) * 72 + q * 8) = o;
            }
        } else if (grp == 0) {
            bf16x8 o;
#pragma unroll
            for (int x = 0; x < 8; ++x) o[x] = 0;
            *reinterpret_cast<bf16x8*>(sV + (w * 16 + i) * 72 + q * 8) = o;
        }
    }
    // no barrier: wave w reads only its own sV strip (within-wave LDS dep)

    int m16 = lane & 15, g = lane >> 4;
    int arow = w * 16 + m16;

    bf16x8 a0 = *reinterpret_cast<const bf16x8*>(sV + arow * 72 + g * 8);
    bf16x8 a1 = *reinterpret_cast<const bf16x8*>(sV + arow * 72 + 32 + g * 8);

    f32x4 acc[4];
#pragma unroll
    for (int c = 0; c < 4; ++c) {
        bf16x8 b0 = *reinterpret_cast<const bf16x8*>(whT + (c * 16 + m16) * 64 + g * 8);
        bf16x8 b1 = *reinterpret_cast<const bf16x8*>(whT + (c * 16 + m16) * 64 + 32 + g * 8);
        f32x4 z = {0.f, 0.f, 0.f, 0.f};
        z = __builtin_amdgcn_mfma_f32_16x16x32_bf16(a0, b0, z, 0, 0, 0);
        z = __builtin_amdgcn_mfma_f32_16x16x32_bf16(a1, b1, z, 0, 0, 0);
        acc[c] = z;
    }
    // C layout: row=(lane>>4)*4+reg, col=c*16+m16
#pragma unroll
    for (int c = 0; c < 4; ++c) {
        float bias = bh[c * 16 + m16];
#pragma unroll
        for (int reg = 0; reg < 4; ++reg) {
            float rv = fmaxf(acc[c][reg] + bias, 0.f);
            sR[(w * 16 + g * 4 + reg) * 72 + c * 16 + m16] = f2bf(rv);
        }
    }

    bf16x8 ra0 = *reinterpret_cast<const bf16x8*>(sR + arow * 72 + g * 8);
    bf16x8 ra1 = *reinterpret_cast<const bf16x8*>(sR + arow * 72 + 32 + g * 8);

    if (storeOut) {
#pragma unroll
        for (int it = 0; it < 2; ++it) {
            int lidx = w * 1024 + it * 512 + lane * 8;
            int row = lidx >> 6;
            if (base + row < N) {
                bf16x8 rv = *reinterpret_cast<const bf16x8*>(sR + row * 72 + (lidx & 63));
                float f[8];
#pragma unroll
                for (int x = 0; x < 8; ++x) f[x] = bf2f((unsigned short)rv[x]);
                *reinterpret_cast<u32x2*>(embOut + (size_t)base * 64 + lidx) = pack8(f);
            }
        }
    }

    f32x4 z[8];
#pragma unroll
    for (int t = 0; t < 8; ++t) {
        bf16x8 b0 = *reinterpret_cast<const bf16x8*>(wfpT + (t * 16 + m16) * 64 + g * 8);
        bf16x8 b1 = *reinterpret_cast<const bf16x8*>(wfpT + (t * 16 + m16) * 64 + 32 + g * 8);
        f32x4 zz = {0.f, 0.f, 0.f, 0.f};
        zz = __builtin_amdgcn_mfma_f32_16x16x32_bf16(ra0, b0, zz, 0, 0, 0);
        zz = __builtin_amdgcn_mfma_f32_16x16x32_bf16(ra1, b1, zz, 0, 0, 0);
        float bias = bfp[t * 16 + m16];
#pragma unroll
        for (int reg = 0; reg < 4; ++reg) zz[reg] += bias;
        z[t] = zz;
    }

#pragma unroll
    for (int reg = 0; reg < 4; ++reg) {
        float mx = -1e30f;
#pragma unroll
        for (int t = 0; t < 8; ++t) mx = fmaxf(mx, z[t][reg]);
#pragma unroll
        for (int d = 1; d < 16; d <<= 1) mx = fmaxf(mx, __shfl_xor(mx, d));
        float s = 0.f;
#pragma unroll
        for (int t = 0; t < 8; ++t) {
            float p = __expf(z[t][reg] - mx);
            z[t][reg] = p;
            s += p;
        }
#pragma unroll
        for (int d = 1; d < 16; d <<= 1) s += __shfl_xor(s, d);
        int node = base + w * 16 + g * 4 + reg;
        float inv = (node < N) ? (1.f / s) : 0.f;
#pragma unroll
        for (int t = 0; t < 8; ++t) z[t][reg] *= inv;
    }
#pragma unroll
    for (int t = 0; t < 8; ++t) {
        float v = z[t][0] + z[t][1] + z[t][2] + z[t][3];
        v += __shfl_xor(v, 16);
        v += __shfl_xor(v, 32);
        if (g == 0) sFp[w][t * 16 + m16] = v;
    }
    __syncthreads();
    if (tid < 128) {
        float s = sFp[0][tid] + sFp[1][tid] + sFp[2][tid] + sFp[3][tid];
        fpart[(size_t)blockIdx.x * 128 + tid] = s;
    }
}

// stage-1 reduce: unrolled multi-accumulator (round-9 lesson)
__global__ __launch_bounds__(256) void reduce1_kernel(const float* __restrict__ fpart,
                                                      float* __restrict__ fred, int nslice) {
    __shared__ float sAcc[128];
    int t = threadIdx.x;
    int col = t & 127, gp = t >> 7;
    int base = blockIdx.x * RSL + gp * (RSL / 2);
    const float* p = fpart + (size_t)base * 128 + col;
    float a0 = 0.f, a1 = 0.f, a2 = 0.f, a3 = 0.f;
    if (base + RSL / 2 <= nslice) {
#pragma unroll
        for (int k = 0; k < 4; ++k) {
            a0 += p[(k * 4 + 0) * 128];
            a1 += p[(k * 4 + 1) * 128];
            a2 += p[(k * 4 + 2) * 128];
            a3 += p[(k * 4 + 3) * 128];
        }
    } else {
        int cnt = nslice - base; if (cnt < 0) cnt = 0;
        for (int k = 0; k < cnt; ++k) a0 += p[k * 128];
    }
    float s = (a0 + a1) + (a2 + a3);
    if (gp == 1) sAcc[col] = s;
    __syncthreads();
    if (gp == 0) fred[(size_t)blockIdx.x * 128 + col] = s + sAcc[col];
}

__global__ __launch_bounds__(256) void final_kernel(const float* __restrict__ fred, int nred,
                                                    const float* __restrict__ Wcl,
                                                    const float* __restrict__ bcl,
                                                    float* __restrict__ out) {
    __shared__ float sAcc[128];
    __shared__ float sf[128];
    __shared__ float logits[10];
    int t = threadIdx.x;
    int col = t & 127, gp = t >> 7;
    int half = (nred + 1) >> 1;
    int b0 = gp * half;
    int b1 = b0 + half; if (b1 > nred) b1 = nred;
    float a0 = 0.f, a1 = 0.f, a2 = 0.f, a3 = 0.f;
    const float* p = fred + col;
    int b = b0;
    for (; b + 4 <= b1; b += 4) {
        a0 += p[(size_t)(b + 0) * 128];
        a1 += p[(size_t)(b + 1) * 128];
        a2 += p[(size_t)(b + 2) * 128];
        a3 += p[(size_t)(b + 3) * 128];
    }
    for (; b < b1; ++b) a0 += p[(size_t)b * 128];
    float s = (a0 + a1) + (a2 + a3);
    if (gp == 1) sAcc[col] = s;
    __syncthreads();
    if (gp == 0) sf[col] = s + sAcc[col];
    __syncthreads();
    if (t < 10) {
        float acc = bcl[t];
        for (int l = 0; l < LFP; l++) acc = fmaf(sf[l], Wcl[l * 10 + t], acc);
        logits[t] = acc;
    }
    __syncthreads();
    if (t == 0) {
        float m = -1e30f;
        for (int i = 0; i < 10; i++) m = fmaxf(m, logits[i]);
        float e[10], s2 = 0.f;
        for (int i = 0; i < 10; i++) { e[i] = __expf(logits[i] - m); s2 += e[i]; }
        for (int i = 0; i < 10; i++) out[i] = e[i] / s2;
    }
}

extern "C" void kernel_launch(void* const* d_in, const int* in_sizes, int n_in,
                              void* d_out, int out_size, void* d_ws, size_t ws_size,
                              hipStream_t stream) {
    const int* feat = (const int*)d_in[0];
    const int* esrc = (const int*)d_in[1];
    const int* edst = (const int*)d_in[2];
    const float* table = (const float*)d_in[3];
    const float* Wh = (const float*)d_in[4];
    const float* bh = (const float*)d_in[5];
    const float* Wfp = (const float*)d_in[6];
    const float* bfp = (const float*)d_in[7];
    const float* Wcl = (const float*)d_in[8];
    const float* bcl = (const float*)d_in[9];
    float* out = (float*)d_out;
    int N = in_sizes[0];
    int nE = in_sizes[1];

    int nbm = (N + BM - 1) / BM;          // round blocks (782)
    int nbc = (N + CB - 1) / CB;          // coarse buckets (98)
    int nbp = (nE + PCHUNK - 1) / PCHUNK; // partition blocks (196)
    int nslice = RROUNDS * nbm;           // 3128
    int nred = (nslice + RSL - 1) / RSL;  // 98

    char* ws = (char*)d_ws;
    size_t off = 0;
    auto alloc = [&](size_t bytes) { void* p = ws + off; off += (bytes + 63) & ~(size_t)63; return p; };
    unsigned char* embA = (unsigned char*)alloc((size_t)N * 64);   // fp8
    unsigned char* embB = (unsigned char*)alloc((size_t)N * 64);   // fp8
    unsigned short* whT  = (unsigned short*)alloc(RROUNDS * 64 * 64 * 2);
    unsigned short* wfpT = (unsigned short*)alloc(RROUNDS * 128 * 64 * 2);
    float* fpart = (float*)alloc((size_t)nslice * 128 * 4);
    float* fred  = (float*)alloc((size_t)nred * 128 * 4);
    int* bucketCount = (int*)alloc(128 * 4);
    int* rp      = (int*)alloc(((size_t)N + 1) * 4);
    int* tmp     = (int*)alloc((size_t)nbc * MAXB * 4);
    unsigned short* csr16 = (unsigned short*)alloc((size_t)nE * 2);

    // setup first: zeroes bucketCount (stream-serial before partition)
    setup_kernel<<<(N * FDIM + 255) / 256, 256, 0, stream>>>(
        feat, table, Wh, Wfp, embA, whT, wfpT, bucketCount, N);

    // single-pass CSR build (rebuilt every call — deterministic, no cross-call state)
    partition_kernel<<<nbp, 256, 0, stream>>>(esrc, edst, bucketCount, tmp, nE, nbc);
    bsort_kernel<<<nbc, 256, 0, stream>>>(bucketCount, tmp, csr16, rp, N, nE, nbc);

    unsigned char* eIn = embA;
    unsigned char* eOut = embB;
    for (int r = 0; r < RROUNDS; ++r) {
        round_kernel<<<nbm, 256, 0, stream>>>(
            eIn, eOut, rp, csr16, whT + (size_t)r * 4096, wfpT + (size_t)r * 8192,
            bh + (size_t)r * FDIM, bfp + (size_t)r * LFP,
            fpart + (size_t)r * nbm * 128, N, (r < RROUNDS - 1) ? 1 : 0);
        unsigned char* t = eIn; eIn = eOut; eOut = t;
    }

    reduce1_kernel<<<nred, 256, 0, stream>>>(fpart, fred, nslice);
    final_kernel<<<1, 256, 0, stream>>>(fred, nred, Wcl, bcl, out);
}